// Round 6
// baseline (4752.062 us; speedup 1.0000x reference)
//
#include <hip/hip_runtime.h>
#include <hip/hip_cooperative_groups.h>
#include <math.h>

namespace cg = cooperative_groups;

#define N 1024
#define D 512
#define NIT 200
#define PIT 50

typedef __attribute__((ext_vector_type(8))) short short8;
typedef __attribute__((ext_vector_type(4))) float floatx4;

// ---------------- helpers ----------------
__device__ __forceinline__ float wave_reduce(float v) {
#pragma unroll
  for (int off = 32; off; off >>= 1) v += __shfl_xor(v, off, 64);
  return v;
}

__device__ __forceinline__ unsigned short f2bf(float x) {
  unsigned int u = __float_as_uint(x);
  u += 0x7FFF + ((u >> 16) & 1);  // round-to-nearest-even
  return (unsigned short)(u >> 16);
}
__device__ __forceinline__ float bf2f(unsigned short h) {
  return __uint_as_float(((unsigned int)h) << 16);
}

// async global->LDS, 16 B per lane; LDS dest must be lane-contiguous
#define GLD16(g, l)                                                     \
  __builtin_amdgcn_global_load_lds(                                     \
      (__attribute__((address_space(1))) void*)(g),                     \
      (__attribute__((address_space(3))) void*)(l), 16, 0, 0)

// ---------------- row normalize ----------------
__global__ __launch_bounds__(256) void normalize_k(
    const float* __restrict__ f1, const float* __restrict__ f2,
    float* __restrict__ Yn, float* __restrict__ An) {
  int b = blockIdx.x;
  const float* src;
  float* dst;
  if (b < N) { src = f1 + (size_t)b * D; dst = Yn + (size_t)b * D; }
  else       { src = f2 + (size_t)(b - N) * D; dst = An + (size_t)(b - N) * D; }
  int tid = threadIdx.x;
  float2 e = ((const float2*)src)[tid];
  float ss = e.x * e.x + e.y * e.y;
  ss = wave_reduce(ss);
  __shared__ float sh[4];
  int lane = tid & 63, wid = tid >> 6;
  if (lane == 0) sh[wid] = ss;
  __syncthreads();
  float total = sh[0] + sh[1] + sh[2] + sh[3];
  float rn = 1.0f / sqrtf(total);
  ((float2*)dst)[tid] = make_float2(e.x * rn, e.y * rn);
}

// ---------------- fp32 NT GEMM (one-time uses: M, YAt, final P) ----------------
#define LDT 68
__global__ __launch_bounds__(256) void gemm_nt(
    const float* __restrict__ A, int lda,
    const float* __restrict__ B, int ldb,
    float* __restrict__ C, int ldc, int K) {
  __shared__ __align__(16) float At[32][LDT];
  __shared__ __align__(16) float Bt[32][LDT];
  const int tid = threadIdx.x;
  const int rowBase = blockIdx.y * 64;
  const int colBase = blockIdx.x * 64;
  const int tx = tid & 15, ty = tid >> 4;
  float acc[4][4] = {};
  const int r0 = tid >> 3;
  const int r1 = r0 + 32;
  const int kc = (tid & 7) * 4;

  for (int k0 = 0; k0 < K; k0 += 32) {
    __syncthreads();
    {
      float4 av = *(const float4*)(A + (size_t)(rowBase + r0) * lda + k0 + kc);
      At[kc + 0][r0] = av.x; At[kc + 1][r0] = av.y; At[kc + 2][r0] = av.z; At[kc + 3][r0] = av.w;
      float4 bv = *(const float4*)(B + (size_t)(colBase + r0) * ldb + k0 + kc);
      Bt[kc + 0][r0] = bv.x; Bt[kc + 1][r0] = bv.y; Bt[kc + 2][r0] = bv.z; Bt[kc + 3][r0] = bv.w;
      av = *(const float4*)(A + (size_t)(rowBase + r1) * lda + k0 + kc);
      At[kc + 0][r1] = av.x; At[kc + 1][r1] = av.y; At[kc + 2][r1] = av.z; At[kc + 3][r1] = av.w;
      bv = *(const float4*)(B + (size_t)(colBase + r1) * ldb + k0 + kc);
      Bt[kc + 0][r1] = bv.x; Bt[kc + 1][r1] = bv.y; Bt[kc + 2][r1] = bv.z; Bt[kc + 3][r1] = bv.w;
    }
    __syncthreads();
#pragma unroll
    for (int kk = 0; kk < 32; ++kk) {
      float4 a4 = *(const float4*)&At[kk][ty * 4];
      float4 b4 = *(const float4*)&Bt[kk][tx * 4];
      float a[4] = {a4.x, a4.y, a4.z, a4.w};
      float b[4] = {b4.x, b4.y, b4.z, b4.w};
#pragma unroll
      for (int r = 0; r < 4; ++r)
#pragma unroll
        for (int c = 0; c < 4; ++c) acc[r][c] = fmaf(a[r], b[c], acc[r][c]);
    }
  }
#pragma unroll
  for (int r = 0; r < 4; ++r) {
    int i = rowBase + ty * 4 + r;
    size_t off = (size_t)i * ldc + colBase + tx * 4;
    *(float4*)(C + off) = make_float4(acc[r][0], acc[r][1], acc[r][2], acc[r][3]);
  }
}

// ================= persistent cooperative kernel ==============================
// 512 blocks x 256 threads, 32 KB LDS (BK=32 dbuf) -> 2 blocks/CU under ANY
// occupancy accounting. Phases: M-split, init, power iteration, Rayleigh,
// 200x (GEMM partial -> grid.sync -> row update -> grid.sync).
__global__ __launch_bounds__(256, 2) void fista_persistent(
    const float* __restrict__ Mm,
    unsigned short* __restrict__ Zh, unsigned short* __restrict__ Zl,
    unsigned short* __restrict__ Mh, unsigned short* __restrict__ Ml,
    const float* __restrict__ YAt,
    float* __restrict__ Vp0, float* __restrict__ Vp1,
    float* __restrict__ vb,     // 3*N floats: v ping, v pong, w
    float* __restrict__ stepP,  // 1 float
    float* __restrict__ Xg) {
  cg::grid_group grid = cg::this_grid();
  // BK=32: each tile buffer 64 rows x 32 shorts = 4 KB; 4 arrays x dbuf = 32 KB
  __shared__ __align__(16) unsigned short sAh[2][64 * 32], sAl[2][64 * 32];
  __shared__ __align__(16) unsigned short sBh[2][64 * 32], sBl[2][64 * 32];
  float* shred = (float*)&sBl[0][0];  // reduction scratch (GEMM idle then)

  const int tid = threadIdx.x;
  const int b = blockIdx.x;
  const int lane = tid & 63, wv = tid >> 6;

  // ---- prologue: split M into bf16 hi/lo (2048 elems per block) ----
  {
    size_t base = ((size_t)b * 2048) + (size_t)tid * 8;
    float4 m0 = *(const float4*)(Mm + base);
    float4 m1 = *(const float4*)(Mm + base + 4);
    ushort4 h0, l0, h1, l1;
    h0.x = f2bf(m0.x); l0.x = f2bf(m0.x - bf2f(h0.x));
    h0.y = f2bf(m0.y); l0.y = f2bf(m0.y - bf2f(h0.y));
    h0.z = f2bf(m0.z); l0.z = f2bf(m0.z - bf2f(h0.z));
    h0.w = f2bf(m0.w); l0.w = f2bf(m0.w - bf2f(h0.w));
    h1.x = f2bf(m1.x); l1.x = f2bf(m1.x - bf2f(h1.x));
    h1.y = f2bf(m1.y); l1.y = f2bf(m1.y - bf2f(h1.y));
    h1.z = f2bf(m1.z); l1.z = f2bf(m1.z - bf2f(h1.z));
    h1.w = f2bf(m1.w); l1.w = f2bf(m1.w - bf2f(h1.w));
    *(ushort4*)(Mh + base) = h0; *(ushort4*)(Mh + base + 4) = h1;
    *(ushort4*)(Ml + base) = l0; *(ushort4*)(Ml + base + 4) = l1;
  }

  // ---- init X/Z register rows + Zh/Zl global + power vector ----
  const int row0 = 2 * b, row1 = row0 + 1;
  const float cinit = 1.0f / (float)N;
  float4 Xr[2], Zr[2], Ya[2];
  Xr[0] = make_float4(cinit, cinit, cinit, cinit);
  Xr[1] = Xr[0]; Zr[0] = Xr[0]; Zr[1] = Xr[0];
  Ya[0] = ((const float4*)(YAt + (size_t)row0 * N))[tid];
  Ya[1] = ((const float4*)(YAt + (size_t)row1 * N))[tid];
  {
    unsigned short zh = f2bf(cinit);
    ushort4 z4; z4.x = zh; z4.y = zh; z4.z = zh; z4.w = zh;
    ushort4 z0; z0.x = 0; z0.y = 0; z0.z = 0; z0.w = 0;
    ((ushort4*)(Zh + (size_t)row0 * N))[tid] = z4;
    ((ushort4*)(Zh + (size_t)row1 * N))[tid] = z4;
    ((ushort4*)(Zl + (size_t)row0 * N))[tid] = z0;
    ((ushort4*)(Zl + (size_t)row1 * N))[tid] = z0;
    if (b == 0) ((float4*)vb)[tid] = make_float4(cinit, cinit, cinit, cinit);
  }
  grid.sync();

  // ---- power iteration: per-step normalization folded into 1/8 scale ----
  int cur = 0;
  for (int i = 0; i < PIT; ++i) {
    if (tid < 128) {
      int row = row0 + (tid >> 6);
      const float* mr = Mm + (size_t)row * N;
      const float* v = vb + cur * N;
      float s = 0.0f;
#pragma unroll
      for (int j = 0; j < N; j += 64) s = fmaf(mr[j + lane], v[j + lane], s);
      s = wave_reduce(s);
      if (lane == 0) vb[(cur ^ 1) * N + row] = s * 0.125f;
    }
    cur ^= 1;
    grid.sync();
  }
  if (tid < 128) {  // final unscaled matvec into w
    int row = row0 + (tid >> 6);
    const float* mr = Mm + (size_t)row * N;
    const float* v = vb + cur * N;
    float s = 0.0f;
#pragma unroll
    for (int j = 0; j < N; j += 64) s = fmaf(mr[j + lane], v[j + lane], s);
    s = wave_reduce(s);
    if (lane == 0) vb[2 * N + row] = s;
  }
  grid.sync();
  if (b == 0) {  // Rayleigh -> step
    const float* u = vb + cur * N;
    const float* w = vb + 2 * N;
    float r1 = 0.0f, r2 = 0.0f;
    for (int j = tid; j < N; j += 256) {
      float uu = u[j];
      r1 = fmaf(uu, w[j], r1);
      r2 = fmaf(uu, uu, r2);
    }
    r1 = wave_reduce(r1);
    r2 = wave_reduce(r2);
    if (lane == 0) { shred[wv] = r1; shred[4 + wv] = r2; }
    __syncthreads();
    if (tid == 0) {
      float R1 = shred[0] + shred[1] + shred[2] + shred[3];
      float R2 = shred[4] + shred[5] + shred[6] + shred[7];
      stepP[0] = 1.0f / (2.0f * (R1 / R2) + 1e-8f);
    }
  }
  grid.sync();
  const float c2 = 2.0f * stepP[0];

  // ---- GEMM tile geometry (XCD swizzle, validated round 4) ----
  const int xcd = b & 7;
  const int jj = b >> 3;
  const int zzK = xcd & 1;
  const int rowBase = (((xcd >> 1) << 2) + (jj >> 4)) * 64;
  const int colBase = (jj & 15) * 64;
  const int kbase = zzK * 512;
  const int wr = (wv >> 1) * 32, wc = (wv & 1) * 32;
  const int q = lane >> 4, m = lane & 15;
  // staging: thread tid loads one 16B chunk per matrix per k-tile.
  // row r = tid>>2, LDS slot = tid&3, global chunk cg = slot ^ (r&3).
  const int sr = tid >> 2;
  const int cg = (tid & 3) ^ (sr & 3);
  const size_t ga = (size_t)(rowBase + sr) * N + cg * 8 + kbase;
  const size_t gb = (size_t)(colBase + sr) * N + cg * 8 + kbase;
  float* Vpout = zzK ? Vp1 : Vp0;

#define ISSUE(buf, koff)                               \
  do {                                                 \
    GLD16(Zh + ga + (koff), &sAh[buf][tid * 8]);       \
    GLD16(Zl + ga + (koff), &sAl[buf][tid * 8]);       \
    GLD16(Mh + gb + (koff), &sBh[buf][tid * 8]);       \
    GLD16(Ml + gb + (koff), &sBl[buf][tid * 8]);       \
  } while (0)

  // ---- FISTA main loop ----
  float tmom = 1.0f;
  for (int it = 0; it < NIT; ++it) {
    // ===== GEMM phase: partial (Z@M) for this tile & K-half =====
    floatx4 acc[2][2];
#pragma unroll
    for (int t = 0; t < 2; ++t)
#pragma unroll
      for (int u = 0; u < 2; ++u) acc[t][u] = (floatx4){0.f, 0.f, 0.f, 0.f};

    ISSUE(0, 0);
    __syncthreads();
    for (int kt = 0; kt < 16; ++kt) {  // 16 k-tiles of 32
      const int curb = kt & 1;
      if (kt + 1 < 16) ISSUE(curb ^ 1, (kt + 1) * 32);
      short8 ah[2], al[2], bh[2], bl[2];
#pragma unroll
      for (int t = 0; t < 2; ++t) {
        int ar = wr + t * 16 + m;
        int sa = ar * 32 + ((q ^ (ar & 3)) & 3) * 8;
        ah[t] = *(const short8*)&sAh[curb][sa];
        al[t] = *(const short8*)&sAl[curb][sa];
        int br = wc + t * 16 + m;
        int sb = br * 32 + ((q ^ (br & 3)) & 3) * 8;
        bh[t] = *(const short8*)&sBh[curb][sb];
        bl[t] = *(const short8*)&sBl[curb][sb];
      }
#pragma unroll
      for (int t = 0; t < 2; ++t)
#pragma unroll
        for (int u = 0; u < 2; ++u) {
          acc[t][u] = __builtin_amdgcn_mfma_f32_16x16x32_bf16(ah[t], bh[u], acc[t][u], 0, 0, 0);
          acc[t][u] = __builtin_amdgcn_mfma_f32_16x16x32_bf16(ah[t], bl[u], acc[t][u], 0, 0, 0);
          acc[t][u] = __builtin_amdgcn_mfma_f32_16x16x32_bf16(al[t], bh[u], acc[t][u], 0, 0, 0);
        }
      __syncthreads();
    }
    // store raw partials; C/D layout col = lane&15, row = (lane>>4)*4 + reg
#pragma unroll
    for (int t = 0; t < 2; ++t) {
      int rowb = rowBase + wr + t * 16 + q * 4;
#pragma unroll
      for (int u = 0; u < 2; ++u) {
        int col = colBase + wc + u * 16 + m;
#pragma unroll
        for (int r = 0; r < 4; ++r)
          Vpout[(size_t)(rowb + r) * N + col] = acc[t][u][r];
      }
    }
    grid.sync();

    // ===== update phase: rows 2b, 2b+1 (X/Z/Ya in registers) =====
    float tn = 0.5f * (1.0f + sqrtf(1.0f + 4.0f * tmom * tmom));
    float mom = (tmom - 1.0f) / tn;
    tmom = tn;
#pragma unroll
    for (int r = 0; r < 2; ++r) {
      const int row = row0 + r;
      float4 a0 = ((const float4*)(Vp0 + (size_t)row * N))[tid];
      float4 a1 = ((const float4*)(Vp1 + (size_t)row * N))[tid];
      float vl[4];
      vl[0] = Zr[r].x - c2 * (a0.x + a1.x - Ya[r].x);
      vl[1] = Zr[r].y - c2 * (a0.y + a1.y - Ya[r].y);
      vl[2] = Zr[r].z - c2 * (a0.z + a1.z - Ya[r].z);
      vl[3] = Zr[r].w - c2 * (a0.w + a1.w - Ya[r].w);

      float s = vl[0] + vl[1] + vl[2] + vl[3];
      s = wave_reduce(s);
      __syncthreads();
      if (lane == 0) shred[wv] = s;
      __syncthreads();
      float theta = (shred[0] + shred[1] + shred[2] + shred[3] - 1.0f) * (1.0f / (float)N);
      for (int itr = 0; itr < 40; ++itr) {  // Michelot fixed point (exact proj)
        float sa = 0.0f, ka = 0.0f;
#pragma unroll
        for (int j = 0; j < 4; ++j)
          if (vl[j] > theta) { sa += vl[j]; ka += 1.0f; }
        sa = wave_reduce(sa);
        ka = wave_reduce(ka);
        __syncthreads();
        if (lane == 0) { shred[wv] = sa; shred[4 + wv] = ka; }
        __syncthreads();
        float SA = shred[0] + shred[1] + shred[2] + shred[3];
        float KA = fmaxf(shred[4] + shred[5] + shred[6] + shred[7], 1.0f);
        float tnn = (SA - 1.0f) / KA;
        bool done = (tnn - theta) <= (1e-7f * fabsf(tnn) + 1e-12f);
        theta = tnn;
        if (done) break;
      }
      float xo[4] = {Xr[r].x, Xr[r].y, Xr[r].z, Xr[r].w};
      float xn[4], zn[4];
#pragma unroll
      for (int j = 0; j < 4; ++j) {
        xn[j] = fmaxf(vl[j] - theta, 0.0f);
        zn[j] = xn[j] + mom * (xn[j] - xo[j]);
      }
      Xr[r] = make_float4(xn[0], xn[1], xn[2], xn[3]);
      Zr[r] = make_float4(zn[0], zn[1], zn[2], zn[3]);
      ushort4 zh4, zl4;
      zh4.x = f2bf(zn[0]); zl4.x = f2bf(zn[0] - bf2f(zh4.x));
      zh4.y = f2bf(zn[1]); zl4.y = f2bf(zn[1] - bf2f(zh4.y));
      zh4.z = f2bf(zn[2]); zl4.z = f2bf(zn[2] - bf2f(zh4.z));
      zh4.w = f2bf(zn[3]); zl4.w = f2bf(zn[3] - bf2f(zh4.w));
      ((ushort4*)(Zh + (size_t)row * N))[tid] = zh4;
      ((ushort4*)(Zl + (size_t)row * N))[tid] = zl4;
    }
    grid.sync();
  }
#undef ISSUE

  ((float4*)(Xg + (size_t)row0 * N))[tid] = Xr[0];
  ((float4*)(Xg + (size_t)row1 * N))[tid] = Xr[1];
}

// ================= fallback path (validated round-4 kernels) ==================
__global__ __launch_bounds__(256) void split_k(const float* __restrict__ Mm,
                                               unsigned short* __restrict__ Mh,
                                               unsigned short* __restrict__ Ml) {
  int i = blockIdx.x * 256 + threadIdx.x;
  float x = Mm[i];
  unsigned short h = f2bf(x);
  Mh[i] = h;
  Ml[i] = f2bf(x - bf2f(h));
}

__global__ __launch_bounds__(256) void init_k(float* __restrict__ X,
                                              unsigned short* __restrict__ Zh,
                                              unsigned short* __restrict__ Zl,
                                              float* __restrict__ v) {
  int i = blockIdx.x * 256 + threadIdx.x;
  const float c = 1.0f / (float)N;
  X[i] = c;
  Zh[i] = f2bf(c);
  Zl[i] = 0;
  if (i < N) v[i] = c;
}

__global__ __launch_bounds__(256) void matvec_k(
    const float* __restrict__ Mm, const float* __restrict__ v,
    float* __restrict__ w, float scale) {
  int tid = threadIdx.x;
  int lane = tid & 63, wid = tid >> 6;
  int row = blockIdx.x * 4 + wid;
  const float* mr = Mm + (size_t)row * N;
  float s = 0.0f;
#pragma unroll
  for (int j = 0; j < N; j += 64) s = fmaf(mr[j + lane], v[j + lane], s);
  s = wave_reduce(s);
  if (lane == 0) w[row] = s * scale;
}

__global__ __launch_bounds__(256) void rayleigh_k(
    const float* __restrict__ u, const float* __restrict__ w,
    float* __restrict__ stepOut) {
  int tid = threadIdx.x;
  float r1 = 0.0f, r2 = 0.0f;
  for (int j = tid; j < N; j += 256) {
    float uu = u[j];
    r1 = fmaf(uu, w[j], r1);
    r2 = fmaf(uu, uu, r2);
  }
  r1 = wave_reduce(r1);
  r2 = wave_reduce(r2);
  __shared__ float sh[8];
  int lane = tid & 63, wid = tid >> 6;
  if (lane == 0) { sh[wid] = r1; sh[4 + wid] = r2; }
  __syncthreads();
  if (tid == 0) {
    float R1 = sh[0] + sh[1] + sh[2] + sh[3];
    float R2 = sh[4] + sh[5] + sh[6] + sh[7];
    stepOut[0] = 1.0f / (2.0f * (R1 / R2) + 1e-8f);
  }
}

#define KTILES 8
__global__ __launch_bounds__(256, 2) void fista_gemm_fb(
    const unsigned short* __restrict__ Zh, const unsigned short* __restrict__ Zl,
    const unsigned short* __restrict__ Mh, const unsigned short* __restrict__ Ml,
    float* __restrict__ Vp) {
  __shared__ __align__(16) unsigned short sAh[2][64 * 64], sAl[2][64 * 64];
  __shared__ __align__(16) unsigned short sBh[2][64 * 64], sBl[2][64 * 64];
  const int tid = threadIdx.x;
  const int g = blockIdx.x + (blockIdx.y << 4) + (blockIdx.z << 8);
  const int xcd = g & 7;
  const int j = g >> 3;
  const int zz = xcd & 1;
  const int rowBase = (((xcd >> 1) << 2) + (j >> 4)) * 64;
  const int colBase = (j & 15) * 64;
  const int kbase = zz * (KTILES * 64);
  const int l = tid & 63;
  const int wid = tid >> 6;
  const int wr = (wid >> 1) * 32;
  const int wc = (wid & 1) * 32;
  const int q = l >> 4, m = l & 15;

  floatx4 acc[2][2];
#pragma unroll
  for (int t = 0; t < 2; ++t)
#pragma unroll
    for (int u = 0; u < 2; ++u) acc[t][u] = (floatx4){0.f, 0.f, 0.f, 0.f};

  const int idx0 = tid, idx1 = 256 + tid;
  const int r0 = idx0 >> 3, c0 = ((idx0 & 7) ^ (r0 & 7)) * 8;
  const int r1 = idx1 >> 3, c1 = ((idx1 & 7) ^ (r1 & 7)) * 8;
  const size_t ga0 = (size_t)(rowBase + r0) * N + c0 + kbase;
  const size_t ga1 = (size_t)(rowBase + r1) * N + c1 + kbase;
  const size_t gb0 = (size_t)(colBase + r0) * N + c0 + kbase;
  const size_t gb1 = (size_t)(colBase + r1) * N + c1 + kbase;

#define ISSUE8(buf, koff)                                  \
  do {                                                     \
    GLD16(Zh + ga0 + (koff), &sAh[buf][idx0 * 8]);         \
    GLD16(Zh + ga1 + (koff), &sAh[buf][idx1 * 8]);         \
    GLD16(Zl + ga0 + (koff), &sAl[buf][idx0 * 8]);         \
    GLD16(Zl + ga1 + (koff), &sAl[buf][idx1 * 8]);         \
    GLD16(Mh + gb0 + (koff), &sBh[buf][idx0 * 8]);         \
    GLD16(Mh + gb1 + (koff), &sBh[buf][idx1 * 8]);         \
    GLD16(Ml + gb0 + (koff), &sBl[buf][idx0 * 8]);         \
    GLD16(Ml + gb1 + (koff), &sBl[buf][idx1 * 8]);         \
  } while (0)

  ISSUE8(0, 0);
  __syncthreads();
  for (int kt = 0; kt < KTILES; ++kt) {
    const int cur = kt & 1;
    if (kt + 1 < KTILES) ISSUE8(cur ^ 1, (kt + 1) * 64);
#pragma unroll
    for (int s = 0; s < 2; ++s) {
      short8 ah[2], al[2], bh[2], bl[2];
#pragma unroll
      for (int t = 0; t < 2; ++t) {
        int ar = wr + t * 16 + m;
        int sa = ((s * 4 + q) ^ (ar & 7)) * 8;
        ah[t] = *(const short8*)&sAh[cur][ar * 64 + sa];
        al[t] = *(const short8*)&sAl[cur][ar * 64 + sa];
        int br = wc + t * 16 + m;
        int sb = ((s * 4 + q) ^ (br & 7)) * 8;
        bh[t] = *(const short8*)&sBh[cur][br * 64 + sb];
        bl[t] = *(const short8*)&sBl[cur][br * 64 + sb];
      }
#pragma unroll
      for (int t = 0; t < 2; ++t)
#pragma unroll
        for (int u = 0; u < 2; ++u) {
          acc[t][u] = __builtin_amdgcn_mfma_f32_16x16x32_bf16(ah[t], bh[u], acc[t][u], 0, 0, 0);
          acc[t][u] = __builtin_amdgcn_mfma_f32_16x16x32_bf16(ah[t], bl[u], acc[t][u], 0, 0, 0);
          acc[t][u] = __builtin_amdgcn_mfma_f32_16x16x32_bf16(al[t], bh[u], acc[t][u], 0, 0, 0);
        }
    }
    __syncthreads();
  }
#undef ISSUE8

  float* out = Vp + (size_t)zz * N * N;
#pragma unroll
  for (int t = 0; t < 2; ++t) {
    int rowb = rowBase + wr + t * 16 + q * 4;
#pragma unroll
    for (int u = 0; u < 2; ++u) {
      int col = colBase + wc + u * 16 + m;
#pragma unroll
      for (int r = 0; r < 4; ++r)
        out[(size_t)(rowb + r) * N + col] = acc[t][u][r];
    }
  }
}

__global__ __launch_bounds__(256) void fista_update_fb(
    const float* __restrict__ Vp0, const float* __restrict__ Vp1,
    const float* __restrict__ YAt, const float* __restrict__ stepPtr,
    float* __restrict__ X,
    unsigned short* __restrict__ Zh, unsigned short* __restrict__ Zl,
    float mom) {
  __shared__ float sh[8];
  const int r = blockIdx.x, tid = threadIdx.x;
  const int lane = tid & 63, wid = tid >> 6;
  const float c2 = 2.0f * stepPtr[0];
  float4 a0 = ((const float4*)(Vp0 + (size_t)r * N))[tid];
  float4 a1 = ((const float4*)(Vp1 + (size_t)r * N))[tid];
  float4 ya = ((const float4*)(YAt + (size_t)r * N))[tid];
  ushort4 zh4 = ((const ushort4*)(Zh + (size_t)r * N))[tid];
  ushort4 zl4 = ((const ushort4*)(Zl + (size_t)r * N))[tid];
  float vl[4];
  vl[0] = bf2f(zh4.x) + bf2f(zl4.x) - c2 * (a0.x + a1.x - ya.x);
  vl[1] = bf2f(zh4.y) + bf2f(zl4.y) - c2 * (a0.y + a1.y - ya.y);
  vl[2] = bf2f(zh4.z) + bf2f(zl4.z) - c2 * (a0.z + a1.z - ya.z);
  vl[3] = bf2f(zh4.w) + bf2f(zl4.w) - c2 * (a0.w + a1.w - ya.w);

  float s = vl[0] + vl[1] + vl[2] + vl[3];
  s = wave_reduce(s);
  if (lane == 0) sh[wid] = s;
  __syncthreads();
  float theta = (sh[0] + sh[1] + sh[2] + sh[3] - 1.0f) * (1.0f / (float)N);
  for (int it = 0; it < 40; ++it) {
    float sa = 0.0f, ka = 0.0f;
#pragma unroll
    for (int j = 0; j < 4; ++j)
      if (vl[j] > theta) { sa += vl[j]; ka += 1.0f; }
    sa = wave_reduce(sa);
    ka = wave_reduce(ka);
    __syncthreads();
    if (lane == 0) { sh[wid] = sa; sh[4 + wid] = ka; }
    __syncthreads();
    float SA = sh[0] + sh[1] + sh[2] + sh[3];
    float KA = fmaxf(sh[4] + sh[5] + sh[6] + sh[7], 1.0f);
    float tn = (SA - 1.0f) / KA;
    bool done = (tn - theta) <= (1e-7f * fabsf(tn) + 1e-12f);
    theta = tn;
    if (done) break;
  }
  float4 x4 = ((const float4*)(X + (size_t)r * N))[tid];
  float xo[4] = {x4.x, x4.y, x4.z, x4.w};
  float xn[4], zn[4];
#pragma unroll
  for (int j = 0; j < 4; ++j) {
    xn[j] = fmaxf(vl[j] - theta, 0.0f);
    zn[j] = xn[j] + mom * (xn[j] - xo[j]);
  }
  ((float4*)(X + (size_t)r * N))[tid] = make_float4(xn[0], xn[1], xn[2], xn[3]);
  ushort4 zh, zl;
  zh.x = f2bf(zn[0]); zl.x = f2bf(zn[0] - bf2f(zh.x));
  zh.y = f2bf(zn[1]); zl.y = f2bf(zn[1] - bf2f(zh.y));
  zh.z = f2bf(zn[2]); zl.z = f2bf(zn[2] - bf2f(zh.z));
  zh.w = f2bf(zn[3]); zl.w = f2bf(zn[3] - bf2f(zh.w));
  ((ushort4*)(Zh + (size_t)r * N))[tid] = zh;
  ((ushort4*)(Zl + (size_t)r * N))[tid] = zl;
}

// ---------------- transpose / cosine / mean ----------------
__global__ void transpose_k(const float* __restrict__ An, float* __restrict__ AnT) {
  __shared__ float t[32][33];
  int x = blockIdx.x * 32 + threadIdx.x;
  int y0 = blockIdx.y * 32;
#pragma unroll
  for (int j = 0; j < 32; j += 8)
    t[threadIdx.y + j][threadIdx.x] = An[(size_t)(y0 + threadIdx.y + j) * D + x];
  __syncthreads();
  int xo = y0 + threadIdx.x;
  int yo0 = blockIdx.x * 32;
#pragma unroll
  for (int j = 0; j < 32; j += 8)
    AnT[(size_t)(yo0 + threadIdx.y + j) * N + xo] = t[threadIdx.x][threadIdx.y + j];
}

__global__ __launch_bounds__(128) void cos_k(const float* __restrict__ P,
                                             const float* __restrict__ Yn,
                                             float* __restrict__ cb) {
  int r = blockIdx.x, tid = threadIdx.x;
  float4 p = ((const float4*)(P + (size_t)r * D))[tid];
  float4 y = ((const float4*)(Yn + (size_t)r * D))[tid];
  float d  = p.x * y.x + p.y * y.y + p.z * y.z + p.w * y.w;
  float np = p.x * p.x + p.y * p.y + p.z * p.z + p.w * p.w;
  float ny = y.x * y.x + y.y * y.y + y.z * y.z + y.w * y.w;
  d = wave_reduce(d);
  np = wave_reduce(np);
  ny = wave_reduce(ny);
  __shared__ float sh[6];
  int lane = tid & 63, wid = tid >> 6;
  if (lane == 0) { sh[wid] = d; sh[2 + wid] = np; sh[4 + wid] = ny; }
  __syncthreads();
  if (tid == 0) {
    float dt = sh[0] + sh[1], npt = sh[2] + sh[3], nyt = sh[4] + sh[5];
    cb[r] = dt / (fmaxf(sqrtf(npt), 1e-8f) * fmaxf(sqrtf(nyt), 1e-8f));
  }
}

__global__ __launch_bounds__(256) void mean_k(const float* __restrict__ cb,
                                              float* __restrict__ out) {
  int tid = threadIdx.x;
  float s = cb[tid] + cb[tid + 256] + cb[tid + 512] + cb[tid + 768];
  s = wave_reduce(s);
  __shared__ float sh[4];
  int lane = tid & 63, wid = tid >> 6;
  if (lane == 0) sh[wid] = s;
  __syncthreads();
  if (tid == 0) out[0] = (sh[0] + sh[1] + sh[2] + sh[3]) * (1.0f / (float)N);
}

// ---------------- host orchestration ----------------
extern "C" void kernel_launch(void* const* d_in, const int* in_sizes, int n_in,
                              void* d_out, int out_size, void* d_ws, size_t ws_size,
                              hipStream_t stream) {
  const float* fea1 = (const float*)d_in[0];
  const float* fea2 = (const float*)d_in[1];
  float* ws = (float*)d_ws;
  float* Yn  = ws;                              // N*D
  float* An  = Yn + (size_t)N * D;              // N*D
  float* Mm  = An + (size_t)N * D;              // N*N
  float* YAt = Mm + (size_t)N * N;              // N*N
  float* Xg  = YAt + (size_t)N * N;             // N*N
  float* Vp0 = Xg + (size_t)N * N;              // N*N
  float* Vp1 = Vp0 + (size_t)N * N;             // N*N
  unsigned short* Zh = (unsigned short*)(Vp1 + (size_t)N * N);  // N*N bf16
  unsigned short* Zl = Zh + (size_t)N * N;
  unsigned short* Mh = Zl + (size_t)N * N;
  unsigned short* Ml = Mh + (size_t)N * N;
  float* vb    = (float*)(Ml + (size_t)N * N);  // 3*N
  float* stepP = vb + 3 * N;
  float* AnT = Vp0;                     // D*N (dead-buffer reuse after loop)
  float* P   = Vp0 + (size_t)N * D;     // N*D
  float* cosb = Mm;

  normalize_k<<<2 * N, 256, 0, stream>>>(fea1, fea2, Yn, An);
  gemm_nt<<<dim3(N / 64, N / 64), 256, 0, stream>>>(An, D, An, D, Mm, N, D);
  gemm_nt<<<dim3(N / 64, N / 64), 256, 0, stream>>>(Yn, D, An, D, YAt, N, D);

  // ---- try cooperative persistent path; fall back to multi-kernel ----
  bool coop = false;
  {
    int maxb = 0;
    if (hipOccupancyMaxActiveBlocksPerMultiprocessor(
            &maxb, (const void*)fista_persistent, 256, 0) == hipSuccess) {
      hipDeviceProp_t prop;
      int dev = 0;
      hipGetDevice(&dev);
      if (hipGetDeviceProperties(&prop, dev) == hipSuccess)
        coop = ((long)maxb * prop.multiProcessorCount >= 512);
    }
  }
  if (coop) {
    const float* Mm_ = Mm;
    unsigned short *Zh_ = Zh, *Zl_ = Zl, *Mh_ = Mh, *Ml_ = Ml;
    const float* YAt_ = YAt;
    float *Vp0_ = Vp0, *Vp1_ = Vp1, *vb_ = vb, *stepP_ = stepP, *Xg_ = Xg;
    void* kargs[] = {(void*)&Mm_, (void*)&Zh_, (void*)&Zl_, (void*)&Mh_,
                     (void*)&Ml_, (void*)&YAt_, (void*)&Vp0_, (void*)&Vp1_,
                     (void*)&vb_, (void*)&stepP_, (void*)&Xg_};
    hipError_t e = hipLaunchCooperativeKernel((const void*)fista_persistent,
                                              dim3(512), dim3(256), kargs, 0,
                                              stream);
    if (e != hipSuccess) {
      (void)hipGetLastError();  // clear sticky error
      coop = false;
    }
  }
  if (!coop) {
    split_k<<<(N * N) / 256, 256, 0, stream>>>(Mm, Mh, Ml);
    init_k<<<(N * N) / 256, 256, 0, stream>>>(Xg, Zh, Zl, vb);
    float* pv = vb;
    float* pw = vb + N;
    for (int i = 0; i < PIT; ++i) {
      matvec_k<<<N / 4, 256, 0, stream>>>(Mm, pv, pw, 0.125f);
      float* t = pv; pv = pw; pw = t;
    }
    matvec_k<<<N / 4, 256, 0, stream>>>(Mm, pv, pw, 1.0f);
    rayleigh_k<<<1, 256, 0, stream>>>(pv, pw, stepP);
    float t = 1.0f;
    for (int it = 0; it < NIT; ++it) {
      fista_gemm_fb<<<dim3(N / 64, N / 64, 2), 256, 0, stream>>>(Zh, Zl, Mh, Ml,
                                                                 Vp0);
      float tn = 0.5f * (1.0f + sqrtf(1.0f + 4.0f * t * t));
      float mom = (t - 1.0f) / tn;
      t = tn;
      fista_update_fb<<<N, 256, 0, stream>>>(Vp0, Vp1, YAt, stepP, Xg, Zh, Zl,
                                             mom);
    }
  }

  transpose_k<<<dim3(D / 32, N / 32), dim3(32, 8), 0, stream>>>(An, AnT);
  gemm_nt<<<dim3(D / 64, N / 64), 256, 0, stream>>>(Xg, N, AnT, N, P, D, N);
  cos_k<<<N, 128, 0, stream>>>(P, Yn, cosb);
  mean_k<<<1, 256, 0, stream>>>(cosb, (float*)d_out);
}